// Round 2
// baseline (1515.359 us; speedup 1.0000x reference)
//
#include <hip/hip_runtime.h>
#include <hip/hip_cooperative_groups.h>
#include <math.h>

namespace cg = cooperative_groups;

// Problem dims (fixed by reference)
#define Bsz 64
#define Ssz 512
#define Hsz 400
#define Dsz 400
#define Vsz 32000
#define Lsz 16
#define H3  1200   // 3*H

// Workspace layout (float offsets).
// Transposed activation tiles: value X[b][k] at (k>>2)*256 + b*4 + (k&3)
#define XQALL_OFF 0                 // 16 * 25600 = 409600
#define HQA_OFF   409600            // 25600
#define HQB_OFF   435200            // 25600
#define GIALL_OFF 460800            // 16 * 1200 * 64 = 1228800
#define GBUF_OFF  1689600           // 2 gates * 4 splits * 1200 * 64 = 614400
#define XQ_OFF    2304000           // 25600  (runtime x, only used when tf==0)
// total 2329600 floats = 9.3 MB of ws

__device__ __forceinline__ int qaddr(int d, int b) {
    return (d >> 2) * (Bsz * 4) + b * 4 + (d & 3);
}

// ---------------------------------------------------------------------------
// Zero the output (131 MB): float4 stores, grid-stride.
// ---------------------------------------------------------------------------
__global__ __launch_bounds__(256) void k_zero(float4* __restrict__ p, int n4,
                                              float* __restrict__ ptail, int ntail) {
    int i = blockIdx.x * 256 + threadIdx.x;
    int stride = gridDim.x * 256;
    float4 z = make_float4(0.f, 0.f, 0.f, 0.f);
    for (; i < n4; i += stride) p[i] = z;
    if (blockIdx.x == 0 && threadIdx.x < ntail) ptail[threadIdx.x] = 0.f;
}

// ---------------------------------------------------------------------------
// Prep: build xq_all[t] (t=0: slot_emb; t>=1: embedding[tgt[:,t-1]] if tf)
// and init hqA = encoded_hidden[0].
// ---------------------------------------------------------------------------
__global__ __launch_bounds__(256) void k_prep(const float* __restrict__ enc_hidden,
                                              const float* __restrict__ slot_emb,
                                              const int* __restrict__ slot_p,
                                              const int* __restrict__ tgt,
                                              const int* __restrict__ tf_p,
                                              const float* __restrict__ embedding,
                                              float* __restrict__ xq_all,
                                              float* __restrict__ hqA) {
    int i = blockIdx.x * 256 + threadIdx.x;
    const int NX = Lsz * Bsz * Dsz;  // 409600
    if (i < NX) {
        int t = i / (Bsz * Dsz);
        int r = i % (Bsz * Dsz);
        int b = r / Dsz;
        int d = r % Dsz;
        float v;
        if (t == 0) {
            v = slot_emb[slot_p[0] * Dsz + d];
        } else if (tf_p[0] != 0) {
            v = embedding[(size_t)tgt[b * Lsz + (t - 1)] * Dsz + d];
        } else {
            v = 0.f;  // unused on the non-teacher-forcing path
        }
        xq_all[t * (Bsz * Dsz) + qaddr(d, b)] = v;
    } else {
        int r = i - NX;
        if (r < Bsz * Hsz) {
            int b = r / Hsz, d = r % Hsz;
            hqA[qaddr(d, b)] = enc_hidden[b * Hsz + d];
        }
    }
}

// ---------------------------------------------------------------------------
// gi_all[t][j][b] = (x_t @ W_ih^T)[b][j]  for all 16 steps at once.
// 2400 wave-units: t in [0,16), 150 j-blocks of 8 rows, full k=400.
// lanes = batch -> W reads wave-uniform.
// ---------------------------------------------------------------------------
__global__ __launch_bounds__(256) void k_gi(const float* __restrict__ W_ih,
                                            const float* __restrict__ xq_all,
                                            float* __restrict__ gi_all) {
    int lane = threadIdx.x & 63;
    int wid  = __builtin_amdgcn_readfirstlane(threadIdx.x >> 6);
    int u = blockIdx.x * 4 + wid;      // 0..2399
    int t = u / 150;
    int j0 = (u % 150) * 8;
    const float4* in4 = (const float4*)(xq_all + t * (Bsz * Dsz));
    float acc[8] = {0.f,0.f,0.f,0.f,0.f,0.f,0.f,0.f};
    for (int k4 = 0; k4 < 100; ++k4) {
        float4 iv = in4[k4 * 64 + lane];
        #pragma unroll
        for (int jj = 0; jj < 8; ++jj) {
            const float4 w4 = *(const float4*)(W_ih + (size_t)(j0 + jj) * Dsz + 4 * k4);
            acc[jj] = fmaf(w4.x, iv.x, acc[jj]);
            acc[jj] = fmaf(w4.y, iv.y, acc[jj]);
            acc[jj] = fmaf(w4.z, iv.z, acc[jj]);
            acc[jj] = fmaf(w4.w, iv.w, acc[jj]);
        }
    }
    float* gout = gi_all + ((size_t)(t * H3 + j0)) * 64 + lane;
    #pragma unroll
    for (int jj = 0; jj < 8; ++jj) gout[jj * 64] = acc[jj];
}

// ---------------------------------------------------------------------------
// Persistent cooperative decoder: 64 blocks (one per batch b) x 1024 threads.
// Per step: phase A (gh GEMM, distributed across grid) -> grid.sync ->
// phase B (finalize GRU, scores s<len, softmax, scatter, pred) -> grid.sync.
// ---------------------------------------------------------------------------
__global__ __launch_bounds__(1024) void k_decoder(const float* __restrict__ gi_all,
                                                  const float* __restrict__ W_ih,
                                                  const float* __restrict__ W_hh,
                                                  const float* __restrict__ b_ih,
                                                  const float* __restrict__ b_hh,
                                                  const float* __restrict__ enc_out,
                                                  const int* __restrict__ lens,
                                                  const int* __restrict__ uttrs,
                                                  const int* __restrict__ tf_p,
                                                  const float* __restrict__ embedding,
                                                  float* __restrict__ hqA,
                                                  float* __restrict__ hqB,
                                                  float* __restrict__ gbuf,
                                                  float* __restrict__ xq,
                                                  float* __restrict__ out_probs,
                                                  float* __restrict__ preds_out) {
    cg::grid_group grid = cg::this_grid();

    __shared__ float4 h4[Hsz / 4];
    float* h_lds = (float*)h4;
    __shared__ float sL[Ssz];
    __shared__ float redv[16];
    __shared__ int   redi[16];
    __shared__ float bc_max, bc_sum;
    __shared__ int   bc_idx;

    const int b    = blockIdx.x;
    const int tid  = threadIdx.x;
    const int lane = tid & 63;
    const int w    = tid >> 6;          // 0..15
    const int tf   = tf_p[0];
    const int len  = lens[b];

    for (int t = 0; t < Lsz; ++t) {
        const float* hq_cur = (t & 1) ? hqB : hqA;
        float*       hq_next = (t & 1) ? hqA : hqB;

        // ---- Phase A: gh = h @ W_hh^T partials (k split in 4), distributed.
        //      When tf==0 and t>0, also gi = x @ W_ih^T from runtime xq.
        {
            int gw = b * 16 + w;  // global wave id 0..1023
            int nunits = (!tf && t > 0) ? 1200 : 600;
            for (int u = gw; u < nunits; u += 1024) {
                int gate  = u / 600;              // 0 = hh, 1 = ih (tf==0 path)
                int rem   = u - gate * 600;
                int split = rem / 150;
                int j0    = (rem - split * 150) * 8;
                int k4beg = split * 25;
                const float*  W   = gate ? W_ih : W_hh;
                const float4* in4 = (const float4*)(gate ? xq : hq_cur);
                float acc[8] = {0.f,0.f,0.f,0.f,0.f,0.f,0.f,0.f};
                for (int k4 = k4beg; k4 < k4beg + 25; ++k4) {
                    float4 iv = in4[k4 * 64 + lane];
                    #pragma unroll
                    for (int jj = 0; jj < 8; ++jj) {
                        const float4 w4 = *(const float4*)(W + (size_t)(j0 + jj) * Hsz + 4 * k4);
                        acc[jj] = fmaf(w4.x, iv.x, acc[jj]);
                        acc[jj] = fmaf(w4.y, iv.y, acc[jj]);
                        acc[jj] = fmaf(w4.z, iv.z, acc[jj]);
                        acc[jj] = fmaf(w4.w, iv.w, acc[jj]);
                    }
                }
                float* gout = gbuf + ((size_t)((gate * 4 + split) * H3 + j0)) * 64 + lane;
                #pragma unroll
                for (int jj = 0; jj < 8; ++jj) gout[jj * 64] = acc[jj];
            }
        }
        grid.sync();

        // ---- Phase B.1: finalize GRU for this block's b.
        for (int d = tid; d < Hsz; d += 1024) {
            float g_r = 0.f, g_z = 0.f, g_n = 0.f;
            #pragma unroll
            for (int sp = 0; sp < 4; ++sp) {
                const float* gb = gbuf + ((size_t)(sp * H3)) * 64 + b;
                g_r += gb[(size_t)d * 64];
                g_z += gb[(size_t)(d + Hsz) * 64];
                g_n += gb[(size_t)(d + 2 * Hsz) * 64];
            }
            float i_r, i_z, i_n;
            if (tf || t == 0) {
                const float* gia = gi_all + (size_t)t * H3 * 64 + b;
                i_r = gia[(size_t)d * 64];
                i_z = gia[(size_t)(d + Hsz) * 64];
                i_n = gia[(size_t)(d + 2 * Hsz) * 64];
            } else {
                i_r = 0.f; i_z = 0.f; i_n = 0.f;
                #pragma unroll
                for (int sp = 0; sp < 4; ++sp) {
                    const float* gb = gbuf + ((size_t)((4 + sp) * H3)) * 64 + b;
                    i_r += gb[(size_t)d * 64];
                    i_z += gb[(size_t)(d + Hsz) * 64];
                    i_n += gb[(size_t)(d + 2 * Hsz) * 64];
                }
            }
            i_r += b_ih[d]; i_z += b_ih[d + Hsz]; i_n += b_ih[d + 2 * Hsz];
            float h_r = g_r + b_hh[d];
            float h_z = g_z + b_hh[d + Hsz];
            float h_n = g_n + b_hh[d + 2 * Hsz];
            float r = 1.f / (1.f + expf(-(i_r + h_r)));
            float z = 1.f / (1.f + expf(-(i_z + h_z)));
            float n = tanhf(i_n + r * h_n);
            float hp = hq_cur[qaddr(d, b)];
            float hn = (1.f - z) * n + z * hp;
            h_lds[d] = hn;
            hq_next[qaddr(d, b)] = hn;
        }
        __syncthreads();

        // ---- Phase B.2: scores for s < len only (masked rows never touched).
        for (int s = w; s < len; s += 16) {
            const float4* e4 = (const float4*)(enc_out + ((size_t)b * Ssz + s) * Hsz);
            float4 ev = e4[lane];
            float4 hv = h4[lane];
            float acc = ev.x * hv.x + ev.y * hv.y + ev.z * hv.z + ev.w * hv.w;
            if (lane < 36) {  // 100 float4 per row: idx 64..99
                float4 ev2 = e4[64 + lane];
                float4 hv2 = h4[64 + lane];
                acc += ev2.x * hv2.x + ev2.y * hv2.y + ev2.z * hv2.z + ev2.w * hv2.w;
            }
            #pragma unroll
            for (int off = 32; off >= 1; off >>= 1) acc += __shfl_xor(acc, off, 64);
            if (lane == 0) sL[s] = acc;
        }
        __syncthreads();

        // ---- Phase B.3: masked max + argmax (first-index tie-break).
        float bv = -INFINITY; int bi = 0x7fffffff;
        for (int s = tid; s < len; s += 1024) {
            float v = sL[s];
            if (v > bv || (v == bv && s < bi)) { bv = v; bi = s; }
        }
        #pragma unroll
        for (int off = 32; off >= 1; off >>= 1) {
            float ov = __shfl_xor(bv, off, 64);
            int   oi = __shfl_xor(bi, off, 64);
            if (ov > bv || (ov == bv && oi < bi)) { bv = ov; bi = oi; }
        }
        if (lane == 0) { redv[w] = bv; redi[w] = bi; }
        __syncthreads();
        if (tid == 0) {
            float mv = redv[0]; int mi = redi[0];
            for (int i = 1; i < 16; ++i)
                if (redv[i] > mv || (redv[i] == mv && redi[i] < mi)) { mv = redv[i]; mi = redi[i]; }
            bc_max = mv; bc_idx = mi;
        }
        __syncthreads();
        float maxv = bc_max;
        int   amax = bc_idx;

        // ---- Phase B.4: exp + sum.
        float ls = 0.f;
        for (int s = tid; s < len; s += 1024) {
            float e = expf(sL[s] - maxv);
            sL[s] = e;
            ls += e;
        }
        #pragma unroll
        for (int off = 32; off >= 1; off >>= 1) ls += __shfl_xor(ls, off, 64);
        if (lane == 0) redv[w] = ls;
        __syncthreads();
        if (tid == 0) {
            float sm = 0.f;
            for (int i = 0; i < 16; ++i) sm += redv[i];
            bc_sum = sm;
        }
        __syncthreads();
        float sum = bc_sum;

        // ---- Phase B.5: scatter probs into vocab bins.
        float* orow = out_probs + (size_t)b * (Lsz * Vsz) + (size_t)t * Vsz;
        for (int s = tid; s < len; s += 1024) {
            atomicAdd(&orow[uttrs[b * Ssz + s]], sL[s] / sum);
        }

        // ---- Phase B.6: pred; next input only needed on the tf==0 path.
        int predtok = uttrs[b * Ssz + amax];
        if (tid == 0) preds_out[(size_t)t * Bsz + b] = (float)predtok;
        if (!tf) {
            const float* erow = embedding + (size_t)predtok * Dsz;
            for (int d = tid; d < Dsz; d += 1024) xq[qaddr(d, b)] = erow[d];
        }
        grid.sync();
    }
}

// ---------------------------------------------------------------------------
extern "C" void kernel_launch(void* const* d_in, const int* in_sizes, int n_in,
                              void* d_out, int out_size, void* d_ws, size_t ws_size,
                              hipStream_t stream) {
    const float* enc_hidden = (const float*)d_in[0];   // [1,B,H]
    const float* enc_out    = (const float*)d_in[1];   // [B,S,H]
    const int*   enc_lens   = (const int*)d_in[2];     // [B]
    const int*   uttrs      = (const int*)d_in[3];     // [B,S]
    const int*   tgt        = (const int*)d_in[4];     // [B,L]
    const int*   slot_p     = (const int*)d_in[5];     // scalar
    const int*   tf_p       = (const int*)d_in[6];     // scalar
    const float* embedding  = (const float*)d_in[7];   // [V,D]
    const float* slot_emb   = (const float*)d_in[8];   // [NSLOTS,D]
    const float* W_ih       = (const float*)d_in[9];   // [3H,D]
    const float* W_hh       = (const float*)d_in[10];  // [3H,H]
    const float* b_ih       = (const float*)d_in[11];  // [3H]
    const float* b_hh       = (const float*)d_in[12];  // [3H]

    float* out = (float*)d_out;
    float* ws  = (float*)d_ws;

    float* xq_all = ws + XQALL_OFF;
    float* hqA    = ws + HQA_OFF;
    float* hqB    = ws + HQB_OFF;
    float* gi_all = ws + GIALL_OFF;
    float* gbuf   = ws + GBUF_OFF;
    float* xq     = ws + XQ_OFF;
    float* preds_out = out + (size_t)Bsz * Lsz * Vsz;

    // 1) zero output (scatter target is ~99% zeros; preds overwritten later)
    int n4 = out_size >> 2;
    int ntail = out_size & 3;
    k_zero<<<2048, 256, 0, stream>>>((float4*)d_out, n4, out + (size_t)n4 * 4, ntail);

    // 2) x_all + h0 prep
    k_prep<<<1701, 256, 0, stream>>>(enc_hidden, slot_emb, slot_p, tgt, tf_p,
                                     embedding, xq_all, hqA);

    // 3) gi_all for all 16 steps in one shot
    k_gi<<<600, 256, 0, stream>>>(W_ih, xq_all, gi_all);

    // 4) persistent cooperative decoder (16 steps, 2 grid syncs/step)
    void* args[] = {
        (void*)&gi_all, (void*)&W_ih, (void*)&W_hh, (void*)&b_ih, (void*)&b_hh,
        (void*)&enc_out, (void*)&enc_lens, (void*)&uttrs, (void*)&tf_p,
        (void*)&embedding, (void*)&hqA, (void*)&hqB, (void*)&gbuf, (void*)&xq,
        (void*)&out, (void*)&preds_out
    };
    hipLaunchCooperativeKernel((const void*)k_decoder, dim3(64), dim3(1024),
                               args, 0, stream);
}

// Round 3
// 1283.720 us; speedup vs baseline: 1.1804x; 1.1804x over previous
//
#include <hip/hip_runtime.h>
#include <hip/hip_cooperative_groups.h>
#include <math.h>

namespace cg = cooperative_groups;

// Problem dims (fixed by reference)
#define Bsz 64
#define Ssz 512
#define Hsz 400
#define Dsz 400
#define Vsz 32000
#define Lsz 16
#define H3  1200   // 3*H

// Workspace layout (float offsets).
// Transposed activation tiles: value X[b][k] at (k>>2)*256 + b*4 + (k&3)
#define XQALL_OFF 0                 // 16 * 25600 = 409600
#define HQA_OFF   409600            // 25600
#define HQB_OFF   435200            // 25600
#define GIALL_OFF 460800            // 16 * 1200 * 64 = 1228800
#define GBUF_OFF  1689600           // 8 * 1200 * 64 = 614400 (fallback uses all, hchain sec 0)
#define XQ_OFF    2304000           // 25600 (runtime x, tf==0 only)
#define HALL_OFF  2329600           // 64 * 16 * 400 = 409600   [b][t][d]
#define SCALL_OFF 2739200           // 16 * 64 * 512 = 524288   [t][b][s]
// total 3263488 floats = 13.1 MB of ws

__device__ __forceinline__ int qaddr(int d, int b) {
    return (d >> 2) * (Bsz * 4) + b * 4 + (d & 3);
}

// ---------------------------------------------------------------------------
// Zero the output (131 MB): float4 stores, grid-stride.
// ---------------------------------------------------------------------------
__global__ __launch_bounds__(256) void k_zero(float4* __restrict__ p, int n4,
                                              float* __restrict__ ptail, int ntail) {
    int i = blockIdx.x * 256 + threadIdx.x;
    int stride = gridDim.x * 256;
    float4 z = make_float4(0.f, 0.f, 0.f, 0.f);
    for (; i < n4; i += stride) p[i] = z;
    if (blockIdx.x == 0 && threadIdx.x < ntail) ptail[threadIdx.x] = 0.f;
}

// ---------------------------------------------------------------------------
// Prep: xq_all[t] (t=0: slot_emb; t>=1: embedding[tgt[:,t-1]] if tf) and
// hqA = encoded_hidden[0] (transposed tile).
// ---------------------------------------------------------------------------
__global__ __launch_bounds__(256) void k_prep(const float* __restrict__ enc_hidden,
                                              const float* __restrict__ slot_emb,
                                              const int* __restrict__ slot_p,
                                              const int* __restrict__ tgt,
                                              const int* __restrict__ tf_p,
                                              const float* __restrict__ embedding,
                                              float* __restrict__ xq_all,
                                              float* __restrict__ hqA) {
    int i = blockIdx.x * 256 + threadIdx.x;
    const int NX = Lsz * Bsz * Dsz;  // 409600
    if (i < NX) {
        int t = i / (Bsz * Dsz);
        int r = i % (Bsz * Dsz);
        int b = r / Dsz;
        int d = r % Dsz;
        float v;
        if (t == 0) {
            v = slot_emb[slot_p[0] * Dsz + d];
        } else if (tf_p[0] != 0) {
            v = embedding[(size_t)tgt[b * Lsz + (t - 1)] * Dsz + d];
        } else {
            v = 0.f;  // unused on the non-teacher-forcing path
        }
        xq_all[t * (Bsz * Dsz) + qaddr(d, b)] = v;
    } else {
        int r = i - NX;
        if (r < Bsz * Hsz) {
            int b = r / Hsz, d = r % Hsz;
            hqA[qaddr(d, b)] = enc_hidden[b * Hsz + d];
        }
    }
}

// ---------------------------------------------------------------------------
// gi_all[t][j][b] = (x_t @ W_ih^T)[b][j]  for all 16 steps at once.
// ---------------------------------------------------------------------------
__global__ __launch_bounds__(256) void k_gi(const float* __restrict__ W_ih,
                                            const float* __restrict__ xq_all,
                                            float* __restrict__ gi_all) {
    int lane = threadIdx.x & 63;
    int wid  = __builtin_amdgcn_readfirstlane(threadIdx.x >> 6);
    int u = blockIdx.x * 4 + wid;      // 0..2399
    int t = u / 150;
    int j0 = (u % 150) * 8;
    const float4* in4 = (const float4*)(xq_all + t * (Bsz * Dsz));
    float acc[8] = {0.f,0.f,0.f,0.f,0.f,0.f,0.f,0.f};
    for (int k4 = 0; k4 < 100; ++k4) {
        float4 iv = in4[k4 * 64 + lane];
        #pragma unroll
        for (int jj = 0; jj < 8; ++jj) {
            const float4 w4 = *(const float4*)(W_ih + (size_t)(j0 + jj) * Dsz + 4 * k4);
            acc[jj] = fmaf(w4.x, iv.x, acc[jj]);
            acc[jj] = fmaf(w4.y, iv.y, acc[jj]);
            acc[jj] = fmaf(w4.z, iv.z, acc[jj]);
            acc[jj] = fmaf(w4.w, iv.w, acc[jj]);
        }
    }
    float* gout = gi_all + ((size_t)(t * H3 + j0)) * 64 + lane;
    #pragma unroll
    for (int jj = 0; jj < 8; ++jj) gout[jj * 64] = acc[jj];
}

// ---------------------------------------------------------------------------
// h-chain (tf==1 only): 16 sequential steps of gh = h@W_hh^T + GRU finalize.
// Cooperative: 64 blocks x 256 threads (256 waves), 2 grid.syncs per step.
// Writes h_all[b][t][d] for the batched attention pass.
// ---------------------------------------------------------------------------
__global__ __launch_bounds__(256) void k_hchain(const float* __restrict__ gi_all,
                                                const float* __restrict__ W_hh,
                                                const float* __restrict__ b_ih,
                                                const float* __restrict__ b_hh,
                                                const int* __restrict__ tf_p,
                                                float* __restrict__ hqA,
                                                float* __restrict__ hqB,
                                                float* __restrict__ gbuf,
                                                float* __restrict__ h_all) {
    if (tf_p[0] == 0) return;  // uniform early-exit, before any sync
    cg::grid_group grid = cg::this_grid();

    int tid  = threadIdx.x;
    int lane = tid & 63;
    int w    = tid >> 6;
    int gw   = blockIdx.x * 4 + w;        // 0..255
    int gtid = blockIdx.x * 256 + tid;    // 0..16383

    for (int t = 0; t < Lsz; ++t) {
        const float* hq_cur  = (t & 1) ? hqB : hqA;
        float*       hq_next = (t & 1) ? hqA : hqB;

        // gh GEMM: 150 wave-units, 8 j-rows each, full k=400.
        if (gw < 150) {
            int j0 = gw * 8;
            const float4* in4 = (const float4*)hq_cur;
            float acc[8] = {0.f,0.f,0.f,0.f,0.f,0.f,0.f,0.f};
            for (int k4 = 0; k4 < 100; ++k4) {
                float4 iv = in4[k4 * 64 + lane];
                #pragma unroll
                for (int jj = 0; jj < 8; ++jj) {
                    const float4 w4 = *(const float4*)(W_hh + (size_t)(j0 + jj) * Hsz + 4 * k4);
                    acc[jj] = fmaf(w4.x, iv.x, acc[jj]);
                    acc[jj] = fmaf(w4.y, iv.y, acc[jj]);
                    acc[jj] = fmaf(w4.z, iv.z, acc[jj]);
                    acc[jj] = fmaf(w4.w, iv.w, acc[jj]);
                }
            }
            float* gout = gbuf + (size_t)j0 * 64 + lane;
            #pragma unroll
            for (int jj = 0; jj < 8; ++jj) gout[jj * 64] = acc[jj];
        }
        grid.sync();

        // finalize: 25600 (d,b) elems over 16384 threads, b fastest (coalesced)
        for (int e = gtid; e < Bsz * Hsz; e += 16384) {
            int b = e & 63;
            int d = e >> 6;
            float h_r = gbuf[(size_t)d * 64 + b]             + b_hh[d];
            float h_z = gbuf[(size_t)(d + Hsz) * 64 + b]     + b_hh[d + Hsz];
            float h_n = gbuf[(size_t)(d + 2 * Hsz) * 64 + b] + b_hh[d + 2 * Hsz];
            const float* gia = gi_all + (size_t)t * H3 * 64;
            float i_r = gia[(size_t)d * 64 + b]             + b_ih[d];
            float i_z = gia[(size_t)(d + Hsz) * 64 + b]     + b_ih[d + Hsz];
            float i_n = gia[(size_t)(d + 2 * Hsz) * 64 + b] + b_ih[d + 2 * Hsz];
            float r = 1.f / (1.f + expf(-(i_r + h_r)));
            float z = 1.f / (1.f + expf(-(i_z + h_z)));
            float n = tanhf(i_n + r * h_n);
            float hp = hq_cur[qaddr(d, b)];
            float hn = (1.f - z) * n + z * hp;
            hq_next[qaddr(d, b)] = hn;
            h_all[(size_t)b * (Lsz * Hsz) + t * Hsz + d] = hn;
        }
        grid.sync();
    }
}

// ---------------------------------------------------------------------------
// Batched scores (tf==1 only): scores_all[t][b][s] = h_t[b] . enc_out[b][s]
// for s < len[b], all 16 t per loaded row. 512 blocks: b = blk>>3, sc = blk&7.
// ---------------------------------------------------------------------------
__global__ __launch_bounds__(256) void k_scores(const float* __restrict__ h_all,
                                                const float* __restrict__ enc_out,
                                                const int* __restrict__ lens,
                                                const int* __restrict__ tf_p,
                                                float* __restrict__ scores_all) {
    if (tf_p[0] == 0) return;
    __shared__ float4 hS[Lsz * 100];   // [t][100] float4 = 25.6 KB

    int b  = blockIdx.x >> 3;
    int sc = blockIdx.x & 7;
    int tid = threadIdx.x;
    int lane = tid & 63;
    int w = tid >> 6;

    const float4* h4g = (const float4*)(h_all + (size_t)b * (Lsz * Hsz));
    for (int i = tid; i < Lsz * 100; i += 256) hS[i] = h4g[i];
    __syncthreads();

    int len = lens[b];
    int l2 = 64 + ((lane < 36) ? lane : 0);   // clamped second-chunk index
    float mult2 = (lane < 36) ? 1.f : 0.f;

    for (int i = 0; i < 16; ++i) {
        int s = sc * 64 + i * 4 + w;
        if (s >= len) continue;
        const float4* e4 = (const float4*)(enc_out + ((size_t)b * Ssz + s) * Hsz);
        float4 ev  = e4[lane];
        float4 ev2 = e4[l2];
        ev2.x *= mult2; ev2.y *= mult2; ev2.z *= mult2; ev2.w *= mult2;

        float acc[Lsz];
        #pragma unroll
        for (int t = 0; t < Lsz; ++t) {
            float4 hv  = hS[t * 100 + lane];
            float4 hv2 = hS[t * 100 + l2];
            float a = ev.x * hv.x + ev.y * hv.y + ev.z * hv.z + ev.w * hv.w;
            a += ev2.x * hv2.x + ev2.y * hv2.y + ev2.z * hv2.z + ev2.w * hv2.w;
            acc[t] = a;
        }
        #pragma unroll
        for (int off = 32; off >= 1; off >>= 1) {
            #pragma unroll
            for (int t = 0; t < Lsz; ++t) acc[t] += __shfl_xor(acc[t], off, 64);
        }
        if (lane == 0) {
            #pragma unroll
            for (int t = 0; t < Lsz; ++t)
                scores_all[(size_t)t * (Bsz * Ssz) + b * Ssz + s] = acc[t];
        }
    }
}

// ---------------------------------------------------------------------------
// Batched softmax + scatter + argmax (tf==1 only): 1024 blocks, one per (t,b).
// ---------------------------------------------------------------------------
__global__ __launch_bounds__(256) void k_softmax_all(const float* __restrict__ scores_all,
                                                     const int* __restrict__ lens,
                                                     const int* __restrict__ uttrs,
                                                     const int* __restrict__ tf_p,
                                                     float* __restrict__ out_probs,
                                                     float* __restrict__ preds_out) {
    if (tf_p[0] == 0) return;
    __shared__ float sL[Ssz];
    __shared__ float redv[4];
    __shared__ int   redi[4];
    __shared__ float bc_max, bc_sum;
    __shared__ int   bc_idx;

    int t = blockIdx.x >> 6;
    int b = blockIdx.x & 63;
    int tid = threadIdx.x;
    int lane = tid & 63, w = tid >> 6;
    int len = lens[b];
    const float* srow = scores_all + (size_t)t * (Bsz * Ssz) + b * Ssz;

    for (int s = tid; s < len; s += 256) sL[s] = srow[s];
    __syncthreads();

    // masked max + argmax (first-index tie-break)
    float bv = -INFINITY; int bi = 0x7fffffff;
    for (int s = tid; s < len; s += 256) {
        float v = sL[s];
        if (v > bv || (v == bv && s < bi)) { bv = v; bi = s; }
    }
    #pragma unroll
    for (int off = 32; off >= 1; off >>= 1) {
        float ov = __shfl_xor(bv, off, 64);
        int   oi = __shfl_xor(bi, off, 64);
        if (ov > bv || (ov == bv && oi < bi)) { bv = ov; bi = oi; }
    }
    if (lane == 0) { redv[w] = bv; redi[w] = bi; }
    __syncthreads();
    if (tid == 0) {
        float mv = redv[0]; int mi = redi[0];
        for (int i = 1; i < 4; ++i)
            if (redv[i] > mv || (redv[i] == mv && redi[i] < mi)) { mv = redv[i]; mi = redi[i]; }
        bc_max = mv; bc_idx = mi;
    }
    __syncthreads();
    float maxv = bc_max;
    int   amax = bc_idx;

    float ls = 0.f;
    for (int s = tid; s < len; s += 256) {
        float e = expf(sL[s] - maxv);
        sL[s] = e;
        ls += e;
    }
    #pragma unroll
    for (int off = 32; off >= 1; off >>= 1) ls += __shfl_xor(ls, off, 64);
    if (lane == 0) redv[w] = ls;
    __syncthreads();
    if (tid == 0) bc_sum = redv[0] + redv[1] + redv[2] + redv[3];
    __syncthreads();
    float sum = bc_sum;

    float* orow = out_probs + (size_t)b * (Lsz * Vsz) + (size_t)t * Vsz;
    for (int s = tid; s < len; s += 256) {
        atomicAdd(&orow[uttrs[b * Ssz + s]], sL[s] / sum);
    }

    if (tid == 0) preds_out[(size_t)t * Bsz + b] = (float)uttrs[b * Ssz + amax];
}

// ---------------------------------------------------------------------------
// Sequential fallback decoder (tf==0 only; early-exit when tf==1).
// ---------------------------------------------------------------------------
__global__ __launch_bounds__(1024) void k_decoder(const float* __restrict__ gi_all,
                                                  const float* __restrict__ W_ih,
                                                  const float* __restrict__ W_hh,
                                                  const float* __restrict__ b_ih,
                                                  const float* __restrict__ b_hh,
                                                  const float* __restrict__ enc_out,
                                                  const int* __restrict__ lens,
                                                  const int* __restrict__ uttrs,
                                                  const int* __restrict__ tf_p,
                                                  const float* __restrict__ embedding,
                                                  float* __restrict__ hqA,
                                                  float* __restrict__ hqB,
                                                  float* __restrict__ gbuf,
                                                  float* __restrict__ xq,
                                                  float* __restrict__ out_probs,
                                                  float* __restrict__ preds_out) {
    if (tf_p[0] != 0) return;  // uniform early-exit before any sync
    cg::grid_group grid = cg::this_grid();

    __shared__ float4 h4[Hsz / 4];
    float* h_lds = (float*)h4;
    __shared__ float sL[Ssz];
    __shared__ float redv[16];
    __shared__ int   redi[16];
    __shared__ float bc_max, bc_sum;
    __shared__ int   bc_idx;

    const int b    = blockIdx.x;
    const int tid  = threadIdx.x;
    const int lane = tid & 63;
    const int w    = tid >> 6;
    const int len  = lens[b];

    for (int t = 0; t < Lsz; ++t) {
        const float* hq_cur = (t & 1) ? hqB : hqA;
        float*       hq_next = (t & 1) ? hqA : hqB;

        {
            int gw = b * 16 + w;
            int nunits = (t > 0) ? 1200 : 600;
            for (int u = gw; u < nunits; u += 1024) {
                int gate  = u / 600;
                int rem   = u - gate * 600;
                int split = rem / 150;
                int j0    = (rem - split * 150) * 8;
                int k4beg = split * 25;
                const float*  W   = gate ? W_ih : W_hh;
                const float4* in4 = (const float4*)(gate ? xq : hq_cur);
                float acc[8] = {0.f,0.f,0.f,0.f,0.f,0.f,0.f,0.f};
                for (int k4 = k4beg; k4 < k4beg + 25; ++k4) {
                    float4 iv = in4[k4 * 64 + lane];
                    #pragma unroll
                    for (int jj = 0; jj < 8; ++jj) {
                        const float4 w4 = *(const float4*)(W + (size_t)(j0 + jj) * Hsz + 4 * k4);
                        acc[jj] = fmaf(w4.x, iv.x, acc[jj]);
                        acc[jj] = fmaf(w4.y, iv.y, acc[jj]);
                        acc[jj] = fmaf(w4.z, iv.z, acc[jj]);
                        acc[jj] = fmaf(w4.w, iv.w, acc[jj]);
                    }
                }
                float* gout = gbuf + ((size_t)((gate * 4 + split) * H3 + j0)) * 64 + lane;
                #pragma unroll
                for (int jj = 0; jj < 8; ++jj) gout[jj * 64] = acc[jj];
            }
        }
        grid.sync();

        for (int d = tid; d < Hsz; d += 1024) {
            float g_r = 0.f, g_z = 0.f, g_n = 0.f;
            #pragma unroll
            for (int sp = 0; sp < 4; ++sp) {
                const float* gb = gbuf + ((size_t)(sp * H3)) * 64 + b;
                g_r += gb[(size_t)d * 64];
                g_z += gb[(size_t)(d + Hsz) * 64];
                g_n += gb[(size_t)(d + 2 * Hsz) * 64];
            }
            float i_r, i_z, i_n;
            if (t == 0) {
                const float* gia = gi_all + (size_t)t * H3 * 64 + b;
                i_r = gia[(size_t)d * 64];
                i_z = gia[(size_t)(d + Hsz) * 64];
                i_n = gia[(size_t)(d + 2 * Hsz) * 64];
            } else {
                i_r = 0.f; i_z = 0.f; i_n = 0.f;
                #pragma unroll
                for (int sp = 0; sp < 4; ++sp) {
                    const float* gb = gbuf + ((size_t)((4 + sp) * H3)) * 64 + b;
                    i_r += gb[(size_t)d * 64];
                    i_z += gb[(size_t)(d + Hsz) * 64];
                    i_n += gb[(size_t)(d + 2 * Hsz) * 64];
                }
            }
            i_r += b_ih[d]; i_z += b_ih[d + Hsz]; i_n += b_ih[d + 2 * Hsz];
            float h_r = g_r + b_hh[d];
            float h_z = g_z + b_hh[d + Hsz];
            float h_n = g_n + b_hh[d + 2 * Hsz];
            float r = 1.f / (1.f + expf(-(i_r + h_r)));
            float z = 1.f / (1.f + expf(-(i_z + h_z)));
            float n = tanhf(i_n + r * h_n);
            float hp = hq_cur[qaddr(d, b)];
            float hn = (1.f - z) * n + z * hp;
            h_lds[d] = hn;
            hq_next[qaddr(d, b)] = hn;
        }
        __syncthreads();

        for (int s = w; s < len; s += 16) {
            const float4* e4 = (const float4*)(enc_out + ((size_t)b * Ssz + s) * Hsz);
            float4 ev = e4[lane];
            float4 hv = h4[lane];
            float acc = ev.x * hv.x + ev.y * hv.y + ev.z * hv.z + ev.w * hv.w;
            if (lane < 36) {
                float4 ev2 = e4[64 + lane];
                float4 hv2 = h4[64 + lane];
                acc += ev2.x * hv2.x + ev2.y * hv2.y + ev2.z * hv2.z + ev2.w * hv2.w;
            }
            #pragma unroll
            for (int off = 32; off >= 1; off >>= 1) acc += __shfl_xor(acc, off, 64);
            if (lane == 0) sL[s] = acc;
        }
        __syncthreads();

        float bv = -INFINITY; int bi = 0x7fffffff;
        for (int s = tid; s < len; s += 1024) {
            float v = sL[s];
            if (v > bv || (v == bv && s < bi)) { bv = v; bi = s; }
        }
        #pragma unroll
        for (int off = 32; off >= 1; off >>= 1) {
            float ov = __shfl_xor(bv, off, 64);
            int   oi = __shfl_xor(bi, off, 64);
            if (ov > bv || (ov == bv && oi < bi)) { bv = ov; bi = oi; }
        }
        if (lane == 0) { redv[w] = bv; redi[w] = bi; }
        __syncthreads();
        if (tid == 0) {
            float mv = redv[0]; int mi = redi[0];
            for (int i = 1; i < 16; ++i)
                if (redv[i] > mv || (redv[i] == mv && redi[i] < mi)) { mv = redv[i]; mi = redi[i]; }
            bc_max = mv; bc_idx = mi;
        }
        __syncthreads();
        float maxv = bc_max;
        int   amax = bc_idx;

        float ls = 0.f;
        for (int s = tid; s < len; s += 1024) {
            float e = expf(sL[s] - maxv);
            sL[s] = e;
            ls += e;
        }
        #pragma unroll
        for (int off = 32; off >= 1; off >>= 1) ls += __shfl_xor(ls, off, 64);
        if (lane == 0) redv[w] = ls;
        __syncthreads();
        if (tid == 0) {
            float sm = 0.f;
            for (int i = 0; i < 16; ++i) sm += redv[i];
            bc_sum = sm;
        }
        __syncthreads();
        float sum = bc_sum;

        float* orow = out_probs + (size_t)b * (Lsz * Vsz) + (size_t)t * Vsz;
        for (int s = tid; s < len; s += 1024) {
            atomicAdd(&orow[uttrs[b * Ssz + s]], sL[s] / sum);
        }

        int predtok = uttrs[b * Ssz + amax];
        if (tid == 0) preds_out[(size_t)t * Bsz + b] = (float)predtok;
        {
            const float* erow = embedding + (size_t)predtok * Dsz;
            for (int d = tid; d < Dsz; d += 1024) xq[qaddr(d, b)] = erow[d];
        }
        grid.sync();
    }
}

// ---------------------------------------------------------------------------
extern "C" void kernel_launch(void* const* d_in, const int* in_sizes, int n_in,
                              void* d_out, int out_size, void* d_ws, size_t ws_size,
                              hipStream_t stream) {
    const float* enc_hidden = (const float*)d_in[0];
    const float* enc_out    = (const float*)d_in[1];
    const int*   enc_lens   = (const int*)d_in[2];
    const int*   uttrs      = (const int*)d_in[3];
    const int*   tgt        = (const int*)d_in[4];
    const int*   slot_p     = (const int*)d_in[5];
    const int*   tf_p       = (const int*)d_in[6];
    const float* embedding  = (const float*)d_in[7];
    const float* slot_emb   = (const float*)d_in[8];
    const float* W_ih       = (const float*)d_in[9];
    const float* W_hh       = (const float*)d_in[10];
    const float* b_ih       = (const float*)d_in[11];
    const float* b_hh       = (const float*)d_in[12];

    float* out = (float*)d_out;
    float* ws  = (float*)d_ws;

    float* xq_all     = ws + XQALL_OFF;
    float* hqA        = ws + HQA_OFF;
    float* hqB        = ws + HQB_OFF;
    float* gi_all     = ws + GIALL_OFF;
    float* gbuf       = ws + GBUF_OFF;
    float* xq         = ws + XQ_OFF;
    float* h_all      = ws + HALL_OFF;
    float* scores_all = ws + SCALL_OFF;
    float* preds_out  = out + (size_t)Bsz * Lsz * Vsz;

    // 1) zero output
    int n4 = out_size >> 2;
    int ntail = out_size & 3;
    k_zero<<<2048, 256, 0, stream>>>((float4*)d_out, n4, out + (size_t)n4 * 4, ntail);

    // 2) x_all + h0 prep
    k_prep<<<1701, 256, 0, stream>>>(enc_hidden, slot_emb, slot_p, tgt, tf_p,
                                     embedding, xq_all, hqA);

    // 3) gi for all 16 steps
    k_gi<<<600, 256, 0, stream>>>(W_ih, xq_all, gi_all);

    // 4) tf==1 fast path: h-chain -> batched scores -> batched softmax/scatter
    {
        void* args[] = {
            (void*)&gi_all, (void*)&W_hh, (void*)&b_ih, (void*)&b_hh,
            (void*)&tf_p, (void*)&hqA, (void*)&hqB, (void*)&gbuf, (void*)&h_all
        };
        hipLaunchCooperativeKernel((const void*)k_hchain, dim3(64), dim3(256),
                                   args, 0, stream);
    }
    k_scores<<<512, 256, 0, stream>>>(h_all, enc_out, enc_lens, tf_p, scores_all);
    k_softmax_all<<<1024, 256, 0, stream>>>(scores_all, enc_lens, uttrs, tf_p,
                                            out, preds_out);

    // 5) tf==0 fallback (early-exits when tf==1)
    {
        void* args[] = {
            (void*)&gi_all, (void*)&W_ih, (void*)&W_hh, (void*)&b_ih, (void*)&b_hh,
            (void*)&enc_out, (void*)&enc_lens, (void*)&uttrs, (void*)&tf_p,
            (void*)&embedding, (void*)&hqA, (void*)&hqB, (void*)&gbuf, (void*)&xq,
            (void*)&out, (void*)&preds_out
        };
        hipLaunchCooperativeKernel((const void*)k_decoder, dim3(64), dim3(1024),
                                   args, 0, stream);
    }
}

// Round 4
// 648.366 us; speedup vs baseline: 2.3372x; 1.9799x over previous
//
#include <hip/hip_runtime.h>
#include <math.h>

// Problem dims (fixed by reference)
#define Bsz 64
#define Ssz 512
#define Hsz 400
#define Dsz 400
#define Vsz 32000
#define Lsz 16
#define H3  1200   // 3*H

// Workspace layout (float offsets)
#define WT_HH_OFF 0                 // 400*1200 transposed W_hh  [k][j]
#define WT_IH_OFF 480000            // 400*1200 transposed W_ih  [k][j]
#define XALL_OFF  960000            // 16*64*400  x_t[t][b][d]
#define GI_OFF    1369600           // 16*64*1200 gi[t][b][j]
#define HALL_OFF  2598400           // 64*16*400  h_all[b][t][d]
#define SCALL_OFF 3008000           // 16*64*512  scores[t][b][s]
// total 3,532,288 floats = 14.1 MB

// ---------------------------------------------------------------------------
// Zero the output (131 MB): float4 stores, grid-stride.
// ---------------------------------------------------------------------------
__global__ __launch_bounds__(256) void k_zero(float4* __restrict__ p, int n4,
                                              float* __restrict__ ptail, int ntail) {
    int i = blockIdx.x * 256 + threadIdx.x;
    int stride = gridDim.x * 256;
    float4 z = make_float4(0.f, 0.f, 0.f, 0.f);
    for (; i < n4; i += stride) p[i] = z;
    if (blockIdx.x == 0 && threadIdx.x < ntail) ptail[threadIdx.x] = 0.f;
}

// ---------------------------------------------------------------------------
// Prep (one kernel, index-range split):
//  [0, 480000)            WT_hh[k*1200+j] = W_hh[j*400+k]
//  [480000, 960000)       WT_ih[k*1200+j] = W_ih[j*400+k]
//  [960000, 1369600)      xall[t][b][d]  (t=0: slot_emb; t>0: embedding[tgt] if tf)
// ---------------------------------------------------------------------------
__global__ __launch_bounds__(256) void k_prep(const float* __restrict__ W_hh,
                                              const float* __restrict__ W_ih,
                                              const float* __restrict__ slot_emb,
                                              const int* __restrict__ slot_p,
                                              const int* __restrict__ tgt,
                                              const int* __restrict__ tf_p,
                                              const float* __restrict__ embedding,
                                              float* __restrict__ ws) {
    int i = blockIdx.x * 256 + threadIdx.x;
    if (i < 480000) {
        int k = i / 1200, j = i % 1200;
        ws[WT_HH_OFF + i] = W_hh[(size_t)j * Hsz + k];
    } else if (i < 960000) {
        int r = i - 480000;
        int k = r / 1200, j = r % 1200;
        ws[WT_IH_OFF + r] = W_ih[(size_t)j * Dsz + k];
    } else {
        int r = i - 960000;   // < 409600
        int t = r / (Bsz * Dsz);
        int rr = r % (Bsz * Dsz);
        int b = rr / Dsz;
        int d = rr % Dsz;
        float v;
        if (t == 0) {
            v = slot_emb[slot_p[0] * Dsz + d];
        } else if (tf_p[0] != 0) {
            v = embedding[(size_t)tgt[b * Lsz + (t - 1)] * Dsz + d];
        } else {
            v = 0.f;  // unused on tf==0 path
        }
        ws[XALL_OFF + r] = v;
    }
}

// ---------------------------------------------------------------------------
// gi[t][b][j] = (x_t[b] @ W_ih^T)[j] for all 16 steps.
// 5120 wave-units: (t, b, jchunk of 256). Lane owns 4 consecutive j.
// WT_ih reads coalesced; x broadcast wave-uniform; stores coalesced.
// ---------------------------------------------------------------------------
__global__ __launch_bounds__(256) void k_gi(const float* __restrict__ ws_ro,
                                            float* __restrict__ gi_all) {
    int lane = threadIdx.x & 63;
    int wid  = __builtin_amdgcn_readfirstlane(threadIdx.x >> 6);
    int u = blockIdx.x * 4 + wid;          // 0..5119
    int t = u / (Bsz * 5);
    int rem = u % (Bsz * 5);
    int b = rem / 5;
    int c = rem % 5;
    int j4 = c * 64 + lane;                // float4 column index, 300 total
    if (j4 >= 300) return;

    const float4* WT4 = (const float4*)(ws_ro + WT_IH_OFF);
    const float*  xv  = ws_ro + XALL_OFF + (size_t)t * (Bsz * Dsz) + b * Dsz;

    float4 acc = make_float4(0.f, 0.f, 0.f, 0.f);
    for (int k = 0; k < Dsz; ++k) {
        float4 wv = WT4[(size_t)k * 300 + j4];
        float x = xv[k];
        acc.x = fmaf(wv.x, x, acc.x);
        acc.y = fmaf(wv.y, x, acc.y);
        acc.z = fmaf(wv.z, x, acc.z);
        acc.w = fmaf(wv.w, x, acc.w);
    }
    ((float4*)(gi_all + ((size_t)(t * Bsz + b)) * H3))[j4] = acc;
}

// ---------------------------------------------------------------------------
// h-chain, tf==1: 64 independent blocks (one per batch), NO cross-block sync.
// Per step: GEMV gh = h @ W_hh^T (threads = 300 j-cols x 3 k-splits),
// then finalize GRU for 400 dims, write h_all[b][t][d]. Only __syncthreads.
// ---------------------------------------------------------------------------
__global__ __launch_bounds__(960) void k_hchain(const float* __restrict__ ws_ro,
                                                const float* __restrict__ gi_all,
                                                const float* __restrict__ enc_hidden,
                                                const float* __restrict__ b_ih,
                                                const float* __restrict__ b_hh,
                                                const int* __restrict__ tf_p,
                                                float* __restrict__ h_all) {
    if (tf_p[0] == 0) return;
    __shared__ float part[3 * H3];
    __shared__ float hx[Hsz];

    const int b   = blockIdx.x;
    const int tid = threadIdx.x;
    const int jc  = tid % 300;
    const int ks  = tid / 300;          // 0..2 (tid>=900 idle in GEMV)
    const int kbeg = ks * 134;
    const int kend = (ks == 2) ? Hsz : kbeg + 134;

    const float4* WT4 = (const float4*)(ws_ro + WT_HH_OFF);

    if (tid < Hsz) hx[tid] = enc_hidden[b * Hsz + tid];
    __syncthreads();

    for (int t = 0; t < Lsz; ++t) {
        if (tid < 900) {
            float4 acc = make_float4(0.f, 0.f, 0.f, 0.f);
            for (int k = kbeg; k < kend; ++k) {
                float4 wv = WT4[(size_t)k * 300 + jc];
                float h = hx[k];
                acc.x = fmaf(wv.x, h, acc.x);
                acc.y = fmaf(wv.y, h, acc.y);
                acc.z = fmaf(wv.z, h, acc.z);
                acc.w = fmaf(wv.w, h, acc.w);
            }
            ((float4*)part)[ks * 300 + jc] = acc;
        }
        __syncthreads();

        if (tid < Hsz) {
            int d = tid;
            float h_r = part[d]            + part[H3 + d]            + part[2 * H3 + d]            + b_hh[d];
            float h_z = part[d + Hsz]      + part[H3 + d + Hsz]      + part[2 * H3 + d + Hsz]      + b_hh[d + Hsz];
            float h_n = part[d + 2 * Hsz]  + part[H3 + d + 2 * Hsz]  + part[2 * H3 + d + 2 * Hsz]  + b_hh[d + 2 * Hsz];
            const float* gia = gi_all + ((size_t)(t * Bsz + b)) * H3;
            float i_r = gia[d]           + b_ih[d];
            float i_z = gia[d + Hsz]     + b_ih[d + Hsz];
            float i_n = gia[d + 2 * Hsz] + b_ih[d + 2 * Hsz];
            float r = 1.f / (1.f + expf(-(i_r + h_r)));
            float z = 1.f / (1.f + expf(-(i_z + h_z)));
            float n = tanhf(i_n + r * h_n);
            float hn = (1.f - z) * n + z * hx[d];
            hx[d] = hn;
            h_all[(size_t)b * (Lsz * Hsz) + t * Hsz + d] = hn;
        }
        __syncthreads();
    }
}

// ---------------------------------------------------------------------------
// Batched scores (tf==1): scores[t][b][s] = h_t[b].enc_out[b][s], s < len[b].
// 512 blocks: b = blk>>3, sc = blk&7; all 16 t per loaded enc row.
// ---------------------------------------------------------------------------
__global__ __launch_bounds__(256) void k_scores(const float* __restrict__ h_all,
                                                const float* __restrict__ enc_out,
                                                const int* __restrict__ lens,
                                                const int* __restrict__ tf_p,
                                                float* __restrict__ scores_all) {
    if (tf_p[0] == 0) return;
    __shared__ float4 hS[Lsz * 100];   // 25.6 KB

    int b  = blockIdx.x >> 3;
    int sc = blockIdx.x & 7;
    int tid = threadIdx.x;
    int lane = tid & 63;
    int w = tid >> 6;

    const float4* h4g = (const float4*)(h_all + (size_t)b * (Lsz * Hsz));
    for (int i = tid; i < Lsz * 100; i += 256) hS[i] = h4g[i];
    __syncthreads();

    int len = lens[b];
    int l2 = 64 + ((lane < 36) ? lane : 0);
    float mult2 = (lane < 36) ? 1.f : 0.f;

    for (int i = 0; i < 16; ++i) {
        int s = sc * 64 + i * 4 + w;
        if (s >= len) continue;
        const float4* e4 = (const float4*)(enc_out + ((size_t)b * Ssz + s) * Hsz);
        float4 ev  = e4[lane];
        float4 ev2 = e4[l2];
        ev2.x *= mult2; ev2.y *= mult2; ev2.z *= mult2; ev2.w *= mult2;

        float acc[Lsz];
        #pragma unroll
        for (int t = 0; t < Lsz; ++t) {
            float4 hv  = hS[t * 100 + lane];
            float4 hv2 = hS[t * 100 + l2];
            float a = ev.x * hv.x + ev.y * hv.y + ev.z * hv.z + ev.w * hv.w;
            a += ev2.x * hv2.x + ev2.y * hv2.y + ev2.z * hv2.z + ev2.w * hv2.w;
            acc[t] = a;
        }
        #pragma unroll
        for (int off = 32; off >= 1; off >>= 1) {
            #pragma unroll
            for (int t = 0; t < Lsz; ++t) acc[t] += __shfl_xor(acc[t], off, 64);
        }
        if (lane == 0) {
            #pragma unroll
            for (int t = 0; t < Lsz; ++t)
                scores_all[(size_t)t * (Bsz * Ssz) + b * Ssz + s] = acc[t];
        }
    }
}

// ---------------------------------------------------------------------------
// Batched softmax + scatter + argmax (tf==1): 1024 blocks, one per (t,b).
// ---------------------------------------------------------------------------
__global__ __launch_bounds__(256) void k_softmax_all(const float* __restrict__ scores_all,
                                                     const int* __restrict__ lens,
                                                     const int* __restrict__ uttrs,
                                                     const int* __restrict__ tf_p,
                                                     float* __restrict__ out_probs,
                                                     float* __restrict__ preds_out) {
    if (tf_p[0] == 0) return;
    __shared__ float sL[Ssz];
    __shared__ float redv[4];
    __shared__ int   redi[4];
    __shared__ float bc_max, bc_sum;
    __shared__ int   bc_idx;

    int t = blockIdx.x >> 6;
    int b = blockIdx.x & 63;
    int tid = threadIdx.x;
    int lane = tid & 63, w = tid >> 6;
    int len = lens[b];
    const float* srow = scores_all + (size_t)t * (Bsz * Ssz) + b * Ssz;

    for (int s = tid; s < len; s += 256) sL[s] = srow[s];
    __syncthreads();

    float bv = -INFINITY; int bi = 0x7fffffff;
    for (int s = tid; s < len; s += 256) {
        float v = sL[s];
        if (v > bv || (v == bv && s < bi)) { bv = v; bi = s; }
    }
    #pragma unroll
    for (int off = 32; off >= 1; off >>= 1) {
        float ov = __shfl_xor(bv, off, 64);
        int   oi = __shfl_xor(bi, off, 64);
        if (ov > bv || (ov == bv && oi < bi)) { bv = ov; bi = oi; }
    }
    if (lane == 0) { redv[w] = bv; redi[w] = bi; }
    __syncthreads();
    if (tid == 0) {
        float mv = redv[0]; int mi = redi[0];
        for (int i = 1; i < 4; ++i)
            if (redv[i] > mv || (redv[i] == mv && redi[i] < mi)) { mv = redv[i]; mi = redi[i]; }
        bc_max = mv; bc_idx = mi;
    }
    __syncthreads();
    float maxv = bc_max;
    int   amax = bc_idx;

    float ls = 0.f;
    for (int s = tid; s < len; s += 256) {
        float e = expf(sL[s] - maxv);
        sL[s] = e;
        ls += e;
    }
    #pragma unroll
    for (int off = 32; off >= 1; off >>= 1) ls += __shfl_xor(ls, off, 64);
    if (lane == 0) redv[w] = ls;
    __syncthreads();
    if (tid == 0) bc_sum = redv[0] + redv[1] + redv[2] + redv[3];
    __syncthreads();
    float sum = bc_sum;

    float* orow = out_probs + (size_t)b * (Lsz * Vsz) + (size_t)t * Vsz;
    for (int s = tid; s < len; s += 256) {
        atomicAdd(&orow[uttrs[b * Ssz + s]], sL[s] / sum);
    }

    if (tid == 0) preds_out[(size_t)t * Bsz + b] = (float)uttrs[b * Ssz + amax];
}

// ---------------------------------------------------------------------------
// tf==0 fallback: 64 fully-independent per-batch blocks, no cross-block sync.
// Each block runs the whole 16-step decode for its b (GEMVs + attention +
// softmax + scatter + argmax + next embedding).
// ---------------------------------------------------------------------------
__global__ __launch_bounds__(960) void k_fallback(const float* __restrict__ ws_ro,
                                                  const float* __restrict__ enc_hidden,
                                                  const float* __restrict__ enc_out,
                                                  const int* __restrict__ lens,
                                                  const int* __restrict__ uttrs,
                                                  const int* __restrict__ slot_p,
                                                  const int* __restrict__ tf_p,
                                                  const float* __restrict__ embedding,
                                                  const float* __restrict__ slot_emb,
                                                  const float* __restrict__ b_ih,
                                                  const float* __restrict__ b_hh,
                                                  float* __restrict__ out_probs,
                                                  float* __restrict__ preds_out) {
    if (tf_p[0] != 0) return;
    __shared__ float part_i[3 * H3];
    __shared__ float part_h[3 * H3];
    __shared__ float hx[Hsz];
    __shared__ float xv[Dsz];
    __shared__ float sL[Ssz];
    __shared__ float redv[15];
    __shared__ int   redi[15];
    __shared__ float bc_max, bc_sum;
    __shared__ int   bc_idx;

    const int b   = blockIdx.x;
    const int tid = threadIdx.x;
    const int lane = tid & 63;
    const int w    = tid >> 6;          // 0..14
    const int jc  = tid % 300;
    const int ks  = tid / 300;
    const int kbeg = ks * 134;
    const int kend = (ks == 2) ? Hsz : kbeg + 134;
    const int len = lens[b];

    const float4* WTH4 = (const float4*)(ws_ro + WT_HH_OFF);
    const float4* WTI4 = (const float4*)(ws_ro + WT_IH_OFF);

    if (tid < Hsz) {
        hx[tid] = enc_hidden[b * Hsz + tid];
        xv[tid] = slot_emb[slot_p[0] * Dsz + tid];
    }
    __syncthreads();

    for (int t = 0; t < Lsz; ++t) {
        if (tid < 900) {
            float4 ai = make_float4(0.f, 0.f, 0.f, 0.f);
            float4 ah = make_float4(0.f, 0.f, 0.f, 0.f);
            for (int k = kbeg; k < kend; ++k) {
                float4 wi = WTI4[(size_t)k * 300 + jc];
                float4 wh = WTH4[(size_t)k * 300 + jc];
                float x = xv[k], h = hx[k];
                ai.x = fmaf(wi.x, x, ai.x); ai.y = fmaf(wi.y, x, ai.y);
                ai.z = fmaf(wi.z, x, ai.z); ai.w = fmaf(wi.w, x, ai.w);
                ah.x = fmaf(wh.x, h, ah.x); ah.y = fmaf(wh.y, h, ah.y);
                ah.z = fmaf(wh.z, h, ah.z); ah.w = fmaf(wh.w, h, ah.w);
            }
            ((float4*)part_i)[ks * 300 + jc] = ai;
            ((float4*)part_h)[ks * 300 + jc] = ah;
        }
        __syncthreads();

        if (tid < Hsz) {
            int d = tid;
            float i_r = part_i[d]           + part_i[H3 + d]           + part_i[2 * H3 + d]           + b_ih[d];
            float i_z = part_i[d + Hsz]     + part_i[H3 + d + Hsz]     + part_i[2 * H3 + d + Hsz]     + b_ih[d + Hsz];
            float i_n = part_i[d + 2 * Hsz] + part_i[H3 + d + 2 * Hsz] + part_i[2 * H3 + d + 2 * Hsz] + b_ih[d + 2 * Hsz];
            float h_r = part_h[d]           + part_h[H3 + d]           + part_h[2 * H3 + d]           + b_hh[d];
            float h_z = part_h[d + Hsz]     + part_h[H3 + d + Hsz]     + part_h[2 * H3 + d + Hsz]     + b_hh[d + Hsz];
            float h_n = part_h[d + 2 * Hsz] + part_h[H3 + d + 2 * Hsz] + part_h[2 * H3 + d + 2 * Hsz] + b_hh[d + 2 * Hsz];
            float r = 1.f / (1.f + expf(-(i_r + h_r)));
            float z = 1.f / (1.f + expf(-(i_z + h_z)));
            float n = tanhf(i_n + r * h_n);
            hx[d] = (1.f - z) * n + z * hx[d];
        }
        __syncthreads();

        // scores for s < len
        const float4* hx4 = (const float4*)hx;
        for (int s = w; s < len; s += 15) {
            const float4* e4 = (const float4*)(enc_out + ((size_t)b * Ssz + s) * Hsz);
            float4 ev = e4[lane];
            float4 hv = hx4[lane];
            float acc = ev.x * hv.x + ev.y * hv.y + ev.z * hv.z + ev.w * hv.w;
            if (lane < 36) {
                float4 ev2 = e4[64 + lane];
                float4 hv2 = hx4[64 + lane];
                acc += ev2.x * hv2.x + ev2.y * hv2.y + ev2.z * hv2.z + ev2.w * hv2.w;
            }
            #pragma unroll
            for (int off = 32; off >= 1; off >>= 1) acc += __shfl_xor(acc, off, 64);
            if (lane == 0) sL[s] = acc;
        }
        __syncthreads();

        // argmax
        float bv = -INFINITY; int bi = 0x7fffffff;
        for (int s = tid; s < len; s += 960) {
            float v = sL[s];
            if (v > bv || (v == bv && s < bi)) { bv = v; bi = s; }
        }
        #pragma unroll
        for (int off = 32; off >= 1; off >>= 1) {
            float ov = __shfl_xor(bv, off, 64);
            int   oi = __shfl_xor(bi, off, 64);
            if (ov > bv || (ov == bv && oi < bi)) { bv = ov; bi = oi; }
        }
        if (lane == 0) { redv[w] = bv; redi[w] = bi; }
        __syncthreads();
        if (tid == 0) {
            float mv = redv[0]; int mi = redi[0];
            for (int i = 1; i < 15; ++i)
                if (redv[i] > mv || (redv[i] == mv && redi[i] < mi)) { mv = redv[i]; mi = redi[i]; }
            bc_max = mv; bc_idx = mi;
        }
        __syncthreads();
        float maxv = bc_max;
        int   amax = bc_idx;

        float ls = 0.f;
        for (int s = tid; s < len; s += 960) {
            float e = expf(sL[s] - maxv);
            sL[s] = e;
            ls += e;
        }
        #pragma unroll
        for (int off = 32; off >= 1; off >>= 1) ls += __shfl_xor(ls, off, 64);
        if (lane == 0) redv[w] = ls;
        __syncthreads();
        if (tid == 0) {
            float sm = 0.f;
            for (int i = 0; i < 15; ++i) sm += redv[i];
            bc_sum = sm;
        }
        __syncthreads();
        float sum = bc_sum;

        float* orow = out_probs + (size_t)b * (Lsz * Vsz) + (size_t)t * Vsz;
        for (int s = tid; s < len; s += 960) {
            atomicAdd(&orow[uttrs[b * Ssz + s]], sL[s] / sum);
        }

        int predtok = uttrs[b * Ssz + amax];
        if (tid == 0) preds_out[(size_t)t * Bsz + b] = (float)predtok;
        __syncthreads();  // sL/scatter done before xv overwrite is fine; hx stable
        if (tid < Dsz) xv[tid] = embedding[(size_t)predtok * Dsz + tid];
        __syncthreads();
    }
}

// ---------------------------------------------------------------------------
extern "C" void kernel_launch(void* const* d_in, const int* in_sizes, int n_in,
                              void* d_out, int out_size, void* d_ws, size_t ws_size,
                              hipStream_t stream) {
    const float* enc_hidden = (const float*)d_in[0];
    const float* enc_out    = (const float*)d_in[1];
    const int*   enc_lens   = (const int*)d_in[2];
    const int*   uttrs      = (const int*)d_in[3];
    const int*   tgt        = (const int*)d_in[4];
    const int*   slot_p     = (const int*)d_in[5];
    const int*   tf_p       = (const int*)d_in[6];
    const float* embedding  = (const float*)d_in[7];
    const float* slot_emb   = (const float*)d_in[8];
    const float* W_ih       = (const float*)d_in[9];
    const float* W_hh       = (const float*)d_in[10];
    const float* b_ih       = (const float*)d_in[11];
    const float* b_hh       = (const float*)d_in[12];

    float* out = (float*)d_out;
    float* ws  = (float*)d_ws;

    float* gi_all     = ws + GI_OFF;
    float* h_all      = ws + HALL_OFF;
    float* scores_all = ws + SCALL_OFF;
    float* preds_out  = out + (size_t)Bsz * Lsz * Vsz;

    // 1) zero output
    int n4 = out_size >> 2;
    int ntail = out_size & 3;
    k_zero<<<2048, 256, 0, stream>>>((float4*)d_out, n4, out + (size_t)n4 * 4, ntail);

    // 2) transposes + x_all  (1,369,600 threads = 5350 * 256 exactly)
    k_prep<<<5350, 256, 0, stream>>>(W_hh, W_ih, slot_emb, slot_p, tgt, tf_p,
                                     embedding, ws);

    // 3) gi for all 16 steps (5120 waves)
    k_gi<<<1280, 256, 0, stream>>>(ws, gi_all);

    // 4) tf==1: per-batch independent h-chain (no grid sync, no coop launch)
    k_hchain<<<64, 960, 0, stream>>>(ws, gi_all, enc_hidden, b_ih, b_hh,
                                     tf_p, h_all);

    // 5) tf==1: batched scores + softmax/scatter
    k_scores<<<512, 256, 0, stream>>>(h_all, enc_out, enc_lens, tf_p, scores_all);
    k_softmax_all<<<1024, 256, 0, stream>>>(scores_all, enc_lens, uttrs, tf_p,
                                            out, preds_out);

    // 6) tf==0 fallback: per-batch independent full decode
    k_fallback<<<64, 960, 0, stream>>>(ws, enc_hidden, enc_out, enc_lens, uttrs,
                                       slot_p, tf_p, embedding, slot_emb,
                                       b_ih, b_hh, out, preds_out);
}